// Round 8
// baseline (116.462 us; speedup 1.0000x reference)
//
#include <hip/hip_runtime.h>

// Inv2d: B=4, C=128, H=W=64, G=8 (16 ch/grp), K=7, dil=2, pad=6,
// reduce 128->32, span 32->392.
//
// Round 8: fuse ker_gen+inv_apply (kills 51 MB ker round-trip + 112 MB
// red re-read + 1 launch) while staying wave-rich (R5's fusion failure
// was 2400 serial ops at 2 blocks/CU; this is ~600 ops at 8 blocks/CU).
//   block = (b,g,h), 2048 blocks, 256 thr.
//   phase1: thread = 1 px, 12-13 taps -> kv row slice (49x64) in LDS.
//           w_span rows wave-uniform -> s_load; red coalesced.
//   phase2: thread = (ch, 4 px): per tap-row 5 float4 x_pad loads
//           (shared by 7 taps) + ds_read_b128 kv + 28 FMA.

#define HW 4096   // 64*64
#define NC 128
#define NR 32
#define KK 49
#define PR 76     // padded rows (6+64+6)
#define PC 80     // padded cols (8+64+8, float4-aligned)

// ---------------------------------------------------------------- red_gen
__global__ __launch_bounds__(256) void red_gen(
    const float* __restrict__ x, const float* __restrict__ w_reduce,
    const float* __restrict__ b_reduce, float* __restrict__ red,
    float* __restrict__ x_pad) {
  // grid: 256 = b(4) x row(64). Block: one 64-px row, all 32 outputs.
  // Also writes x_pad interior row + this block's share of border zeros.
  __shared__ float xs[NC][64];       // 32 KB
  int t = threadIdx.x;
  int blk = blockIdx.x;
  int b = blk >> 6;
  int row = blk & 63;
  int p0 = row * 64;

  // ---- border zeroing: 992 of batch-b's 63488 border float4s ----
  {
    float4 z = make_float4(0.f, 0.f, 0.f, 0.f);
    float* xpb0 = x_pad + (size_t)b * NC * PR * PC;
#pragma unroll
    for (int it = 0; it < 4; ++it) {
      int local = it * 256 + t;
      if (local < 992) {
        int f = row * 992 + local;       // 0..63487
        int plane = f / 496;
        int k = f - plane * 496;
        int d;
        if (k < 120) d = k;                       // rows 0..5 (all 20 f4)
        else if (k < 240) d = k - 120 + 70 * 20;  // rows 70..75
        else {
          int k2 = k - 240;                       // rows 6..69, side cols
          int rr = 6 + (k2 >> 2);
          int c4 = k2 & 3;                        // f4 col 0,1,18,19
          d = rr * 20 + ((c4 < 2) ? c4 : 16 + c4);
        }
        *(float4*)(xpb0 + (size_t)plane * PR * PC + d * 4) = z;
      }
    }
  }

  const float* xb = x + b * NC * HW + p0;
  float* xpb = x_pad + ((size_t)(b * NC) * PR + (row + 6)) * PC + 8;
  int fx = t & 15;
  int c0 = t >> 4;
#pragma unroll
  for (int r = 0; r < 8; ++r) {
    int c = c0 + 16 * r;
    float4 v = *(const float4*)(xb + c * HW + fx * 4);
    *(float4*)(&xs[c][fx * 4]) = v;
    *(float4*)(xpb + (size_t)c * PR * PC + fx * 4) = v;  // x_pad interior
  }
  __syncthreads();

  int px = t & 63;
  int quad = __builtin_amdgcn_readfirstlane(t >> 6);  // wave-uniform octet
  const float* wq = w_reduce + quad * 8 * NC;         // scalar (s_load) base

  float acc[8];
#pragma unroll
  for (int j = 0; j < 8; ++j) acc[j] = b_reduce[quad * 8 + j];

#pragma unroll 8
  for (int k = 0; k < NC; ++k) {
    float xk = xs[k][px];
#pragma unroll
    for (int j = 0; j < 8; ++j) acc[j] += xk * wq[j * NC + k];
  }

  float* rp = red + (b * NR + quad * 8) * HW + p0 + px;
#pragma unroll
  for (int j = 0; j < 8; ++j) rp[j * HW] = acc[j];
}

// ---------------------------------------------------------------- ker_apply
__global__ __launch_bounds__(256) void ker_apply(
    const float* __restrict__ x_pad, const float* __restrict__ red,
    const float* __restrict__ w_span, const float* __restrict__ b_span,
    float* __restrict__ out) {
  // grid: 2048 = h(64) x g(8) x b(4); block: 256 thr, one output row
  __shared__ float kvs[KK * 64];     // 12.25 KB
  int blk = blockIdx.x;
  int h = blk & 63;
  int g = (blk >> 6) & 7;
  int b = blk >> 9;
  int tid = threadIdx.x;

  // ---- phase 1: 49x64 dynamic-kernel row slice -> LDS ----
  {
    int px = tid & 63;
    int wv = tid >> 6;               // wave id 0..3 (uniform)

    float r[NR];
    const float* rp = red + b * NR * HW + h * 64 + px;
#pragma unroll
    for (int o = 0; o < NR; ++o) r[o] = rp[o * HW];

    int ntap = (wv == 3) ? 13 : 12;  // taps wv*12 .. (wave-uniform bound)
#pragma unroll
    for (int t = 0; t < 13; ++t) {
      if (t < ntap) {
        int tp = wv * 12 + t;
        const float* wrow = w_span + (g * KK + tp) * NR;  // uniform -> s_load
        float s0 = b_span[g * KK + tp], s1 = 0.f;
#pragma unroll
        for (int o = 0; o < NR; o += 2) {
          s0 = fmaf(r[o], wrow[o], s0);
          s1 = fmaf(r[o + 1], wrow[o + 1], s1);
        }
        kvs[tp * 64 + px] = s0 + s1;  // lanes = consecutive px, no conflict
      }
    }
  }
  __syncthreads();

  // ---- phase 2: apply to 16 channels ----
  int c = tid >> 4;                  // channel in group
  int pxq = tid & 15;                // pixel quad (cols 4*pxq..4*pxq+3)
  const float* xrow =
      x_pad + ((size_t)(b * NC + g * 16 + c) * PR + h) * PC + 4 * pxq;

  float a0 = 0.f, a1 = 0.f, a2 = 0.f, a3 = 0.f;
#pragma unroll
  for (int i = 0; i < 7; ++i) {
    const float* pr = xrow + 2 * i * PC;
    float xr[20];
#pragma unroll
    for (int m = 0; m < 5; ++m) {
      float4 v = *(const float4*)(pr + 4 * m);
      xr[4 * m] = v.x; xr[4 * m + 1] = v.y;
      xr[4 * m + 2] = v.z; xr[4 * m + 3] = v.w;
    }
#pragma unroll
    for (int j = 0; j < 7; ++j) {
      float4 kv = *(const float4*)(&kvs[(i * 7 + j) * 64 + 4 * pxq]);
      a0 = fmaf(xr[2 + 2 * j], kv.x, a0);
      a1 = fmaf(xr[3 + 2 * j], kv.y, a1);
      a2 = fmaf(xr[4 + 2 * j], kv.z, a2);
      a3 = fmaf(xr[5 + 2 * j], kv.w, a3);
    }
  }

  float* op = out + (size_t)(b * NC + g * 16 + c) * HW + h * 64 + 4 * pxq;
  *(float4*)op = make_float4(a0, a1, a2, a3);
}

extern "C" void kernel_launch(void* const* d_in, const int* in_sizes, int n_in,
                              void* d_out, int out_size, void* d_ws, size_t ws_size,
                              hipStream_t stream) {
  const float* x        = (const float*)d_in[0];  // [4,128,64,64]
  const float* w_reduce = (const float*)d_in[1];  // [32,128]
  const float* b_reduce = (const float*)d_in[2];  // [32]
  const float* w_span   = (const float*)d_in[3];  // [392,32]
  const float* b_span   = (const float*)d_in[4];  // [392]
  float* out = (float*)d_out;                     // [4,128,64,64]

  float* red   = (float*)d_ws;                    // 4*32*4096   = 2 MB
  float* x_pad = red + 4 * NR * HW;               // 4*128*76*80 = 12.5 MB

  red_gen<<<256, 256, 0, stream>>>(x, w_reduce, b_reduce, red, x_pad);
  ker_apply<<<2048, 256, 0, stream>>>(x_pad, red, w_span, b_span, out);
}

// Round 10
// 101.724 us; speedup vs baseline: 1.1449x; 1.1449x over previous
//
#include <hip/hip_runtime.h>

// Inv2d: B=4, C=128, H=W=64, G=8 (16 ch/grp), K=7, dil=2, pad=6,
// reduce 128->32, span 32->392.
//
// Round 10: R9's NaN was an OOB: ker_gen's grid treated the per-(b,g)
// pixel space as 16384 but it is HW=4096 -> red_bf reads ran into x_pad
// (fp32 bits as bf16 -> NaN patterns) and ker stores ran across tap rows.
// Fixed decomposition: block = 256 px of one (b,g); wave wv owns 64 px
// in 4 iterations of 16. Grid 512 = pxc(16) x g(8) x b(4).
// Everything else as R9 (MFMA bf16 ker_gen, R7-proven red_gen/inv_apply).

#define HW 4096   // 64*64
#define NC 128
#define NR 32
#define KK 49
#define PR 76     // padded rows (6+64+6)
#define PC 80     // padded cols (8+64+8, float4-aligned)
#define KSTR 136  // inv_apply LDS per-tap stride (2 rows x 68)

typedef __attribute__((ext_vector_type(8))) short short8;
typedef __attribute__((ext_vector_type(4))) float f32x4;

__device__ __forceinline__ unsigned short f2bf(float f) {
  unsigned int u = __float_as_uint(f);
  u = (u + 0x7fffu + ((u >> 16) & 1u)) >> 16;   // RNE
  return (unsigned short)u;
}

// ---------------------------------------------------------------- red_gen
__global__ __launch_bounds__(256) void red_gen(
    const float* __restrict__ x, const float* __restrict__ w_reduce,
    const float* __restrict__ b_reduce, unsigned short* __restrict__ red_bf,
    float* __restrict__ x_pad) {
  // grid: 256 = b(4) x row(64). Block: one 64-px row, all 32 outputs.
  // Also writes x_pad interior row + this block's share of border zeros.
  __shared__ float xs[NC][64];       // 32 KB
  int t = threadIdx.x;
  int blk = blockIdx.x;
  int b = blk >> 6;
  int row = blk & 63;
  int p0 = row * 64;

  // ---- border zeroing: 992 of batch-b's 63488 border float4s ----
  {
    float4 z = make_float4(0.f, 0.f, 0.f, 0.f);
    float* xpb0 = x_pad + (size_t)b * NC * PR * PC;
#pragma unroll
    for (int it = 0; it < 4; ++it) {
      int local = it * 256 + t;
      if (local < 992) {
        int f = row * 992 + local;       // 0..63487
        int plane = f / 496;
        int k = f - plane * 496;
        int d;
        if (k < 120) d = k;                       // rows 0..5 (all 20 f4)
        else if (k < 240) d = k - 120 + 70 * 20;  // rows 70..75
        else {
          int k2 = k - 240;                       // rows 6..69, side cols
          int rr = 6 + (k2 >> 2);
          int c4 = k2 & 3;                        // f4 col 0,1,18,19
          d = rr * 20 + ((c4 < 2) ? c4 : 16 + c4);
        }
        *(float4*)(xpb0 + (size_t)plane * PR * PC + d * 4) = z;
      }
    }
  }

  const float* xb = x + b * NC * HW + p0;
  float* xpb = x_pad + ((size_t)(b * NC) * PR + (row + 6)) * PC + 8;
  int fx = t & 15;
  int c0 = t >> 4;
#pragma unroll
  for (int r = 0; r < 8; ++r) {
    int c = c0 + 16 * r;
    float4 v = *(const float4*)(xb + c * HW + fx * 4);
    *(float4*)(&xs[c][fx * 4]) = v;
    *(float4*)(xpb + (size_t)c * PR * PC + fx * 4) = v;  // x_pad interior
  }
  __syncthreads();

  int px = t & 63;
  int quad = __builtin_amdgcn_readfirstlane(t >> 6);  // wave-uniform octet
  const float* wq = w_reduce + quad * 8 * NC;         // scalar (s_load) base

  float acc[8];
#pragma unroll
  for (int j = 0; j < 8; ++j) acc[j] = b_reduce[quad * 8 + j];

#pragma unroll 8
  for (int k = 0; k < NC; ++k) {
    float xk = xs[k][px];
#pragma unroll
    for (int j = 0; j < 8; ++j) acc[j] += xk * wq[j * NC + k];
  }

  // red^T bf16: [b][px][32 o], one 16B store (o-octet = quad*8..+7)
  union { short8 v; unsigned short u[8]; } pk;
#pragma unroll
  for (int j = 0; j < 8; ++j) pk.u[j] = f2bf(acc[j]);
  *(short8*)(red_bf + ((size_t)(b * HW) + p0 + px) * NR + quad * 8) = pk.v;
}

// ---------------------------------------------------------------- ker_gen (MFMA)
__global__ __launch_bounds__(256) void ker_gen(
    const unsigned short* __restrict__ red_bf, const float* __restrict__ w_span,
    const float* __restrict__ b_span, float* __restrict__ ker) {
  // grid: 512 = pxc(16) x g(8) x b(4); block: 4 waves, 256 px of one (b,g)
  // per (b,g): ker[64 taps(pad)][4096 px] = W[64][32] x redT[4096][32]^T + b
  __shared__ short wlds[64 * 32];    // bf16 W tile, 4 KB (taps 49..63 = 0)
  __shared__ float bsl[64];

  int tid = threadIdx.x;
  int blk = blockIdx.x;
  int pxc = blk & 15;                // 256-px chunk within the batch
  int g = (blk >> 4) & 7;
  int b = blk >> 7;
  int l = tid & 63;
  int wv = __builtin_amdgcn_readfirstlane(tid >> 6);  // wave id 0..3
  int quad = l >> 4;
  int mn = l & 15;

  // stage W (fp32 -> bf16) + bias into LDS
  const float* wg = w_span + g * KK * NR;            // 1568 floats
#pragma unroll
  for (int it = 0; it < 8; ++it) {
    int idx = it * 256 + tid;
    wlds[idx] = (idx < KK * NR) ? (short)f2bf(wg[idx]) : (short)0;
  }
  if (tid < 64) bsl[tid] = (tid < KK) ? b_span[g * KK + tid] : 0.f;
  __syncthreads();

  // A-fragments: A[m=lane&15][k=quad*8+j] from LDS (16B aligned)
  short8 af[4];
#pragma unroll
  for (int tt = 0; tt < 4; ++tt)
    af[tt] = *(const short8*)(&wlds[(tt * 16 + mn) * NR + quad * 8]);

  // bias as MFMA C-operand: C/D row = quad*4+reg, col = lane&15
  f32x4 ci[4];
#pragma unroll
  for (int tt = 0; tt < 4; ++tt) {
#pragma unroll
    for (int r = 0; r < 4; ++r) ci[tt][r] = bsl[tt * 16 + quad * 4 + r];
  }

  // wave wv covers px [pxc*256 + wv*64, +64) in 4 iters of 16 px
  int px0 = pxc * 256 + wv * 64;     // < 4096 always
  const unsigned short* rb = red_bf + ((size_t)b * HW + px0 + mn) * NR + quad * 8;
  float* kp = ker + (size_t)((b * 8 + g) * KK) * HW + px0 + mn;

#pragma unroll
  for (int it = 0; it < 4; ++it) {
    short8 bf = *(const short8*)(rb + (size_t)it * 16 * NR);
    f32x4 d0 = __builtin_amdgcn_mfma_f32_16x16x32_bf16(af[0], bf, ci[0], 0, 0, 0);
    f32x4 d1 = __builtin_amdgcn_mfma_f32_16x16x32_bf16(af[1], bf, ci[1], 0, 0, 0);
    f32x4 d2 = __builtin_amdgcn_mfma_f32_16x16x32_bf16(af[2], bf, ci[2], 0, 0, 0);
    f32x4 d3 = __builtin_amdgcn_mfma_f32_16x16x32_bf16(af[3], bf, ci[3], 0, 0, 0);
    float* kpi = kp + it * 16;
#pragma unroll
    for (int r = 0; r < 4; ++r) {
      kpi[(size_t)(0 * 16 + quad * 4 + r) * HW] = d0[r];
      kpi[(size_t)(1 * 16 + quad * 4 + r) * HW] = d1[r];
      kpi[(size_t)(2 * 16 + quad * 4 + r) * HW] = d2[r];
    }
    if (quad == 0) kpi[(size_t)48 * HW] = d3[0];   // only tap 48 of tile 3
  }
}

// ---------------------------------------------------------------- inv_apply
__global__ __launch_bounds__(256) void inv_apply(
    const float* __restrict__ x_pad, const float* __restrict__ ker,
    float* __restrict__ out) {
  // grid: 1024 = hpair(32) x g(8) x b(4)
  // block: 256 thr = 16 ch x 2 rows x 8 col-octets; thread = 1 ch, 8 px
  __shared__ float kvs[KK * KSTR];   // 26.7 KB
  int blk = blockIdx.x;
  int hp = blk & 31;
  int g = (blk >> 5) & 7;
  int b = blk >> 8;
  int tid = threadIdx.x;
  int h0 = hp * 2;

  // stage ker[b,g,:, rows h0..h0+1] -> LDS
  const float* kerbg = ker + ((size_t)(b * 8 + g) * KK) * HW + h0 * 64;
#pragma unroll
  for (int it = 0; it < 7; ++it) {
    int idx4 = it * 256 + tid;
    if (idx4 < KK * 32) {
      int tp = idx4 >> 5;            // tap
      int rem = idx4 & 31;           // r*16 + c4
      int r = rem >> 4, c4 = rem & 15;
      float4 v = *(const float4*)(kerbg + (size_t)tp * HW + rem * 4);
      *(float4*)(&kvs[tp * KSTR + r * 68 + c4 * 4]) = v;
    }
  }
  __syncthreads();

  int c = tid >> 4;                  // channel in group
  int sub = tid & 15;
  int r = sub >> 3;                  // row 0..1
  int oct = sub & 7;                 // col octet
  int h = h0 + r;

  const float* xrow =
      x_pad + ((size_t)(b * NC + g * 16 + c) * PR + h) * PC + 8 * oct;
  float2 a0 = {0.f, 0.f}, a1 = {0.f, 0.f}, a2 = {0.f, 0.f}, a3 = {0.f, 0.f};

#pragma unroll
  for (int i = 0; i < 7; ++i) {
    const float* pr = xrow + 2 * i * PC;
    float xr[24];
#pragma unroll
    for (int m = 0; m < 6; ++m) {
      float4 v = *(const float4*)(pr + 4 * m);
      xr[4 * m] = v.x; xr[4 * m + 1] = v.y;
      xr[4 * m + 2] = v.z; xr[4 * m + 3] = v.w;
    }
#pragma unroll
    for (int j = 0; j < 7; ++j) {
      const float* kb = &kvs[(i * 7 + j) * KSTR + r * 68 + 8 * oct];
      float4 k0 = *(const float4*)(kb);
      float4 k1 = *(const float4*)(kb + 4);
      a0.x = fmaf(xr[2 + 2 * j], k0.x, a0.x);
      a0.y = fmaf(xr[3 + 2 * j], k0.y, a0.y);
      a1.x = fmaf(xr[4 + 2 * j], k0.z, a1.x);
      a1.y = fmaf(xr[5 + 2 * j], k0.w, a1.y);
      a2.x = fmaf(xr[6 + 2 * j], k1.x, a2.x);
      a2.y = fmaf(xr[7 + 2 * j], k1.y, a2.y);
      a3.x = fmaf(xr[8 + 2 * j], k1.z, a3.x);
      a3.y = fmaf(xr[9 + 2 * j], k1.w, a3.y);
    }
  }

  float* op = out + (size_t)(b * NC + g * 16 + c) * HW + h * 64 + 8 * oct;
  *(float4*)op = make_float4(a0.x, a0.y, a1.x, a1.y);
  *(float4*)(op + 4) = make_float4(a2.x, a2.y, a3.x, a3.y);
}

extern "C" void kernel_launch(void* const* d_in, const int* in_sizes, int n_in,
                              void* d_out, int out_size, void* d_ws, size_t ws_size,
                              hipStream_t stream) {
  const float* x        = (const float*)d_in[0];  // [4,128,64,64]
  const float* w_reduce = (const float*)d_in[1];  // [32,128]
  const float* b_reduce = (const float*)d_in[2];  // [32]
  const float* w_span   = (const float*)d_in[3];  // [392,32]
  const float* b_span   = (const float*)d_in[4];  // [392]
  float* out = (float*)d_out;                     // [4,128,64,64]

  unsigned short* red_bf = (unsigned short*)d_ws;        // 4*4096*32 bf16 = 1 MB
  float* x_pad = (float*)((char*)d_ws + (1 << 20));      // 4*128*76*80  = 12.5 MB
  float* ker   = x_pad + (size_t)4 * NC * PR * PC;       // 4*8*49*4096  = 25.7 MB

  red_gen<<<256, 256, 0, stream>>>(x, w_reduce, b_reduce, red_bf, x_pad);
  ker_gen<<<512, 256, 0, stream>>>(red_bf, w_span, b_span, ker);
  inv_apply<<<1024, 256, 0, stream>>>(x_pad, ker, out);
}

// Round 11
// 101.044 us; speedup vs baseline: 1.1526x; 1.0067x over previous
//
#include <hip/hip_runtime.h>

// Inv2d: B=4, C=128, H=W=64, G=8 (16 ch/grp), K=7, dil=2, pad=6,
// reduce 128->32, span 32->392.
//
// Round 11: R10 structure (proven: 101.7us, absmax 0.031) with ker stored
// as bf16 (values are already bf16-MFMA-accurate; fp32 storage was waste).
// ker round-trip 51 MB -> 25.6 MB. inv_apply converts bf16->fp32 during
// LDS staging (~24 VALU/thread); kvs layout + apply loop unchanged.

#define HW 4096   // 64*64
#define NC 128
#define NR 32
#define KK 49
#define PR 76     // padded rows (6+64+6)
#define PC 80     // padded cols (8+64+8, float4-aligned)
#define KSTR 136  // inv_apply LDS per-tap stride (2 rows x 68)

typedef __attribute__((ext_vector_type(8))) short short8;
typedef __attribute__((ext_vector_type(4))) float f32x4;

__device__ __forceinline__ unsigned short f2bf(float f) {
  unsigned int u = __float_as_uint(f);
  u = (u + 0x7fffu + ((u >> 16) & 1u)) >> 16;   // RNE
  return (unsigned short)u;
}
__device__ __forceinline__ float bf2f(unsigned short u) {
  return __uint_as_float(((unsigned int)u) << 16);
}

// ---------------------------------------------------------------- red_gen
__global__ __launch_bounds__(256) void red_gen(
    const float* __restrict__ x, const float* __restrict__ w_reduce,
    const float* __restrict__ b_reduce, unsigned short* __restrict__ red_bf,
    float* __restrict__ x_pad) {
  // grid: 256 = b(4) x row(64). Block: one 64-px row, all 32 outputs.
  // Also writes x_pad interior row + this block's share of border zeros.
  __shared__ float xs[NC][64];       // 32 KB
  int t = threadIdx.x;
  int blk = blockIdx.x;
  int b = blk >> 6;
  int row = blk & 63;
  int p0 = row * 64;

  // ---- border zeroing: 992 of batch-b's 63488 border float4s ----
  {
    float4 z = make_float4(0.f, 0.f, 0.f, 0.f);
    float* xpb0 = x_pad + (size_t)b * NC * PR * PC;
#pragma unroll
    for (int it = 0; it < 4; ++it) {
      int local = it * 256 + t;
      if (local < 992) {
        int f = row * 992 + local;       // 0..63487
        int plane = f / 496;
        int k = f - plane * 496;
        int d;
        if (k < 120) d = k;                       // rows 0..5 (all 20 f4)
        else if (k < 240) d = k - 120 + 70 * 20;  // rows 70..75
        else {
          int k2 = k - 240;                       // rows 6..69, side cols
          int rr = 6 + (k2 >> 2);
          int c4 = k2 & 3;                        // f4 col 0,1,18,19
          d = rr * 20 + ((c4 < 2) ? c4 : 16 + c4);
        }
        *(float4*)(xpb0 + (size_t)plane * PR * PC + d * 4) = z;
      }
    }
  }

  const float* xb = x + b * NC * HW + p0;
  float* xpb = x_pad + ((size_t)(b * NC) * PR + (row + 6)) * PC + 8;
  int fx = t & 15;
  int c0 = t >> 4;
#pragma unroll
  for (int r = 0; r < 8; ++r) {
    int c = c0 + 16 * r;
    float4 v = *(const float4*)(xb + c * HW + fx * 4);
    *(float4*)(&xs[c][fx * 4]) = v;
    *(float4*)(xpb + (size_t)c * PR * PC + fx * 4) = v;  // x_pad interior
  }
  __syncthreads();

  int px = t & 63;
  int quad = __builtin_amdgcn_readfirstlane(t >> 6);  // wave-uniform octet
  const float* wq = w_reduce + quad * 8 * NC;         // scalar (s_load) base

  float acc[8];
#pragma unroll
  for (int j = 0; j < 8; ++j) acc[j] = b_reduce[quad * 8 + j];

#pragma unroll 8
  for (int k = 0; k < NC; ++k) {
    float xk = xs[k][px];
#pragma unroll
    for (int j = 0; j < 8; ++j) acc[j] += xk * wq[j * NC + k];
  }

  // red^T bf16: [b][px][32 o], one 16B store (o-octet = quad*8..+7)
  union { short8 v; unsigned short u[8]; } pk;
#pragma unroll
  for (int j = 0; j < 8; ++j) pk.u[j] = f2bf(acc[j]);
  *(short8*)(red_bf + ((size_t)(b * HW) + p0 + px) * NR + quad * 8) = pk.v;
}

// ---------------------------------------------------------------- ker_gen (MFMA)
__global__ __launch_bounds__(256) void ker_gen(
    const unsigned short* __restrict__ red_bf, const float* __restrict__ w_span,
    const float* __restrict__ b_span, unsigned short* __restrict__ ker) {
  // grid: 512 = pxc(16) x g(8) x b(4); block: 4 waves, 256 px of one (b,g)
  // per (b,g): ker[64 taps(pad)][4096 px] = W[64][32] x redT[4096][32]^T + b
  __shared__ short wlds[64 * 32];    // bf16 W tile, 4 KB (taps 49..63 = 0)
  __shared__ float bsl[64];

  int tid = threadIdx.x;
  int blk = blockIdx.x;
  int pxc = blk & 15;                // 256-px chunk within the batch
  int g = (blk >> 4) & 7;
  int b = blk >> 7;
  int l = tid & 63;
  int wv = __builtin_amdgcn_readfirstlane(tid >> 6);  // wave id 0..3
  int quad = l >> 4;
  int mn = l & 15;

  // stage W (fp32 -> bf16) + bias into LDS
  const float* wg = w_span + g * KK * NR;            // 1568 floats
#pragma unroll
  for (int it = 0; it < 8; ++it) {
    int idx = it * 256 + tid;
    wlds[idx] = (idx < KK * NR) ? (short)f2bf(wg[idx]) : (short)0;
  }
  if (tid < 64) bsl[tid] = (tid < KK) ? b_span[g * KK + tid] : 0.f;
  __syncthreads();

  // A-fragments: A[m=lane&15][k=quad*8+j] from LDS (16B aligned)
  short8 af[4];
#pragma unroll
  for (int tt = 0; tt < 4; ++tt)
    af[tt] = *(const short8*)(&wlds[(tt * 16 + mn) * NR + quad * 8]);

  // bias as MFMA C-operand: C/D row = quad*4+reg, col = lane&15
  f32x4 ci[4];
#pragma unroll
  for (int tt = 0; tt < 4; ++tt) {
#pragma unroll
    for (int r = 0; r < 4; ++r) ci[tt][r] = bsl[tt * 16 + quad * 4 + r];
  }

  // wave wv covers px [pxc*256 + wv*64, +64) in 4 iters of 16 px
  int px0 = pxc * 256 + wv * 64;     // < 4096 always
  const unsigned short* rb = red_bf + ((size_t)b * HW + px0 + mn) * NR + quad * 8;
  unsigned short* kp = ker + (size_t)((b * 8 + g) * KK) * HW + px0 + mn;

#pragma unroll
  for (int it = 0; it < 4; ++it) {
    short8 bf = *(const short8*)(rb + (size_t)it * 16 * NR);
    f32x4 d0 = __builtin_amdgcn_mfma_f32_16x16x32_bf16(af[0], bf, ci[0], 0, 0, 0);
    f32x4 d1 = __builtin_amdgcn_mfma_f32_16x16x32_bf16(af[1], bf, ci[1], 0, 0, 0);
    f32x4 d2 = __builtin_amdgcn_mfma_f32_16x16x32_bf16(af[2], bf, ci[2], 0, 0, 0);
    f32x4 d3 = __builtin_amdgcn_mfma_f32_16x16x32_bf16(af[3], bf, ci[3], 0, 0, 0);
    unsigned short* kpi = kp + it * 16;
#pragma unroll
    for (int r = 0; r < 4; ++r) {
      kpi[(size_t)(0 * 16 + quad * 4 + r) * HW] = f2bf(d0[r]);
      kpi[(size_t)(1 * 16 + quad * 4 + r) * HW] = f2bf(d1[r]);
      kpi[(size_t)(2 * 16 + quad * 4 + r) * HW] = f2bf(d2[r]);
    }
    if (quad == 0) kpi[(size_t)48 * HW] = f2bf(d3[0]);  // only tap 48
  }
}

// ---------------------------------------------------------------- inv_apply
__global__ __launch_bounds__(256) void inv_apply(
    const float* __restrict__ x_pad, const unsigned short* __restrict__ ker,
    float* __restrict__ out) {
  // grid: 1024 = hpair(32) x g(8) x b(4)
  // block: 256 thr = 16 ch x 2 rows x 8 col-octets; thread = 1 ch, 8 px
  __shared__ float kvs[KK * KSTR];   // 26.7 KB
  int blk = blockIdx.x;
  int hp = blk & 31;
  int g = (blk >> 5) & 7;
  int b = blk >> 8;
  int tid = threadIdx.x;
  int h0 = hp * 2;

  // stage ker[b,g,:, rows h0..h0+1] (bf16) -> fp32 LDS
  const unsigned short* kerbg = ker + ((size_t)(b * 8 + g) * KK) * HW + h0 * 64;
#pragma unroll
  for (int it = 0; it < 4; ++it) {
    int idx = it * 256 + tid;
    if (idx < KK * 16) {             // 784 ushort8 chunks (16B each)
      int tp = idx >> 4;             // tap
      int m = idx & 15;              // 8-px chunk within the 128-px row-pair
      short8 v = *(const short8*)(kerbg + (size_t)tp * HW + m * 8);
      int pxl = m * 8;
      int r = pxl >> 6, col = pxl & 63;
      float* dst = &kvs[tp * KSTR + r * 68 + col];
      *(float4*)(dst) = make_float4(
          bf2f((unsigned short)v[0]), bf2f((unsigned short)v[1]),
          bf2f((unsigned short)v[2]), bf2f((unsigned short)v[3]));
      *(float4*)(dst + 4) = make_float4(
          bf2f((unsigned short)v[4]), bf2f((unsigned short)v[5]),
          bf2f((unsigned short)v[6]), bf2f((unsigned short)v[7]));
    }
  }
  __syncthreads();

  int c = tid >> 4;                  // channel in group
  int sub = tid & 15;
  int r = sub >> 3;                  // row 0..1
  int oct = sub & 7;                 // col octet
  int h = h0 + r;

  const float* xrow =
      x_pad + ((size_t)(b * NC + g * 16 + c) * PR + h) * PC + 8 * oct;
  float2 a0 = {0.f, 0.f}, a1 = {0.f, 0.f}, a2 = {0.f, 0.f}, a3 = {0.f, 0.f};

#pragma unroll
  for (int i = 0; i < 7; ++i) {
    const float* pr = xrow + 2 * i * PC;
    float xr[24];
#pragma unroll
    for (int m = 0; m < 6; ++m) {
      float4 v = *(const float4*)(pr + 4 * m);
      xr[4 * m] = v.x; xr[4 * m + 1] = v.y;
      xr[4 * m + 2] = v.z; xr[4 * m + 3] = v.w;
    }
#pragma unroll
    for (int j = 0; j < 7; ++j) {
      const float* kb = &kvs[(i * 7 + j) * KSTR + r * 68 + 8 * oct];
      float4 k0 = *(const float4*)(kb);
      float4 k1 = *(const float4*)(kb + 4);
      a0.x = fmaf(xr[2 + 2 * j], k0.x, a0.x);
      a0.y = fmaf(xr[3 + 2 * j], k0.y, a0.y);
      a1.x = fmaf(xr[4 + 2 * j], k0.z, a1.x);
      a1.y = fmaf(xr[5 + 2 * j], k0.w, a1.y);
      a2.x = fmaf(xr[6 + 2 * j], k1.x, a2.x);
      a2.y = fmaf(xr[7 + 2 * j], k1.y, a2.y);
      a3.x = fmaf(xr[8 + 2 * j], k1.z, a3.x);
      a3.y = fmaf(xr[9 + 2 * j], k1.w, a3.y);
    }
  }

  float* op = out + (size_t)(b * NC + g * 16 + c) * HW + h * 64 + 8 * oct;
  *(float4*)op = make_float4(a0.x, a0.y, a1.x, a1.y);
  *(float4*)(op + 4) = make_float4(a2.x, a2.y, a3.x, a3.y);
}

extern "C" void kernel_launch(void* const* d_in, const int* in_sizes, int n_in,
                              void* d_out, int out_size, void* d_ws, size_t ws_size,
                              hipStream_t stream) {
  const float* x        = (const float*)d_in[0];  // [4,128,64,64]
  const float* w_reduce = (const float*)d_in[1];  // [32,128]
  const float* b_reduce = (const float*)d_in[2];  // [32]
  const float* w_span   = (const float*)d_in[3];  // [392,32]
  const float* b_span   = (const float*)d_in[4];  // [392]
  float* out = (float*)d_out;                     // [4,128,64,64]

  unsigned short* red_bf = (unsigned short*)d_ws;        // 4*4096*32 bf16 = 1 MB
  float* x_pad = (float*)((char*)d_ws + (1 << 20));      // 4*128*76*80  = 12.5 MB
  unsigned short* ker =                                   // 4*8*49*4096 bf16 = 12.8 MB
      (unsigned short*)(x_pad + (size_t)4 * NC * PR * PC);

  red_gen<<<256, 256, 0, stream>>>(x, w_reduce, b_reduce, red_bf, x_pad);
  ker_gen<<<512, 256, 0, stream>>>(red_bf, w_span, b_span, ker);
  inv_apply<<<1024, 256, 0, stream>>>(x_pad, ker, out);
}